// Round 12
// baseline (1320.122 us; speedup 1.0000x reference)
//
#include <hip/hip_runtime.h>

#define NN 10000
#define STRD 10272  // bf16 panel/adjb row stride (elements)
#define KSPLIT 16   // K-slices
#define VSTEPS 20   // K-steps of 32 per block
#define FEAT 2048
#define HID 128
#define NCLS 64

typedef short s16x8 __attribute__((ext_vector_type(8)));
typedef float f32x4 __attribute__((ext_vector_type(4)));

static __device__ __forceinline__ unsigned short f2bf(float f) {
  unsigned int u = __float_as_uint(f);
  u += 0x7FFFu + ((u >> 16) & 1u);
  return (unsigned short)(u >> 16);
}

#define MFMA16(accv, av, bv) \
  (accv) = __builtin_amdgcn_mfma_f32_16x16x32_bf16((av), (bv), (accv), 0, 0, 0)

#define FENCE_ANCHOR() do { asm volatile("" ::: "memory"); __builtin_amdgcn_sched_barrier(0); } while (0)

__device__ __forceinline__ void vmwait(int n) {
  switch (n) {
    case 0: asm volatile("s_waitcnt vmcnt(0)" ::: "memory"); break;
    case 1: asm volatile("s_waitcnt vmcnt(1)" ::: "memory"); break;
    case 2: asm volatile("s_waitcnt vmcnt(2)" ::: "memory"); break;
    case 3: asm volatile("s_waitcnt vmcnt(3)" ::: "memory"); break;
    case 4: asm volatile("s_waitcnt vmcnt(4)" ::: "memory"); break;
    case 5: asm volatile("s_waitcnt vmcnt(5)" ::: "memory"); break;
    default: asm volatile("s_waitcnt vmcnt(6)" ::: "memory"); break;
  }
}

// Self-calibration of the MFMA C/D lane->(m,n) mapping (proved correct in R2).
__device__ __forceinline__ void calib_mn(int lane, int* cm, int* cn) {
  const int lr = lane & 15;
  const int lg = lane >> 4;
  s16x8 pa, pb;
#pragma unroll
  for (int j = 0; j < 8; ++j) { pa[j] = 0; pb[j] = 0; }
  if (lg == 0) {
    pa[0] = (short)f2bf(1.0f);
    pa[1] = (short)f2bf((float)(1 + lr));
    pb[0] = (short)f2bf((float)(128 * (1 + lr)));
    pb[1] = (short)f2bf(1.0f);
  }
  f32x4 acc;
#pragma unroll
  for (int j = 0; j < 4; ++j) acc[j] = 0.f;
  MFMA16(acc, pa, pb);
#pragma unroll
  for (int r = 0; r < 4; ++r) {
    const int v = (int)acc[r];
    cm[r] = (v & 127) - 1;
    cn[r] = (v >> 7) - 1;
  }
}

__global__ void zero_f32_kernel(float* __restrict__ p, int n) {
  int i = blockIdx.x * 256 + threadIdx.x;
  if (i < n) p[i] = 0.f;
}

// prep: transpose W1, W2 to bf16; zero pad columns of the 3 bf16 p-panels
__global__ void prep_kernel(const float* __restrict__ W1, const float* __restrict__ W2,
                            unsigned short* __restrict__ W1T, unsigned short* __restrict__ W2T,
                            unsigned short* __restrict__ HT, unsigned short* __restrict__ pA,
                            unsigned short* __restrict__ pB) {
  const int idx = blockIdx.x * 256 + threadIdx.x;
  if (idx < FEAT * HID) {
    const int k = idx / HID, c = idx % HID;
    W1T[(size_t)c * FEAT + k] = f2bf(W1[idx]);
  }
  if (idx < HID * NCLS) {
    const int k = idx / NCLS, c = idx % NCLS;
    W2T[(size_t)c * HID + k] = f2bf(W2[idx]);
  }
  if (idx < 3 * 64 * (STRD - NN)) {
    const int span = 64 * (STRD - NN);
    const int p = idx / span;
    const int rem = idx % span;
    const int c = rem / (STRD - NN);
    const int col = NN + rem % (STRD - NN);
    unsigned short* pan = (p == 0) ? HT : ((p == 1) ? pA : pB);
    pan[(size_t)c * STRD + col] = 0;
  }
}

// ---------------- MLP layer 1 ----------------
__global__ __launch_bounds__(256) void mlp1_kernel(
    const float* __restrict__ X, const unsigned short* __restrict__ W1T,
    const float* __restrict__ b1, unsigned short* __restrict__ H1) {
  __shared__ float red[4][16][HID];
  const int tid = threadIdx.x, wv = tid >> 6, lane = tid & 63;
  const int lr = lane & 15, lg = lane >> 4;
  const int r0 = blockIdx.x * 16;
  int cm[4], cn[4];
  calib_mn(lane, cm, cn);

  f32x4 acc[8];
#pragma unroll
  for (int t = 0; t < 8; ++t)
#pragma unroll
    for (int j = 0; j < 4; ++j) acc[t][j] = 0.f;

  for (int s = wv * 16; s < wv * 16 + 16; ++s) {
    const int kg = s * 32 + 8 * lg;
    const float* px = X + (size_t)(r0 + lr) * FEAT + kg;
    const float4 xa = *(const float4*)(px);
    const float4 xb = *(const float4*)(px + 4);
    s16x8 af;
    af[0] = (short)f2bf(xa.x); af[1] = (short)f2bf(xa.y);
    af[2] = (short)f2bf(xa.z); af[3] = (short)f2bf(xa.w);
    af[4] = (short)f2bf(xb.x); af[5] = (short)f2bf(xb.y);
    af[6] = (short)f2bf(xb.z); af[7] = (short)f2bf(xb.w);
#pragma unroll
    for (int t = 0; t < 8; ++t) {
      const s16x8 bf = *(const s16x8*)(W1T + (size_t)(16 * t + lr) * FEAT + kg);
      MFMA16(acc[t], af, bf);
    }
  }
#pragma unroll
  for (int t = 0; t < 8; ++t)
#pragma unroll
    for (int r = 0; r < 4; ++r)
      red[wv][cm[r]][16 * t + cn[r]] = acc[t][r];
  __syncthreads();

  const int row = tid >> 4;
  const int c0 = (tid & 15) * 8;
  s16x8 hv;
#pragma unroll
  for (int j = 0; j < 8; ++j) {
    float v = red[0][row][c0 + j] + red[1][row][c0 + j] +
              red[2][row][c0 + j] + red[3][row][c0 + j] + b1[c0 + j];
    v = fmaxf(v, 0.f);
    hv[j] = (short)f2bf(v);
  }
  *(s16x8*)(H1 + (size_t)(r0 + row) * HID + c0) = hv;
}

// ---------------- MLP layer 2 -> HT (bf16 64 x STRD) + out init ----------------
__global__ __launch_bounds__(256) void mlp2_kernel(
    const unsigned short* __restrict__ H1, const unsigned short* __restrict__ W2T,
    const float* __restrict__ b2, const float* __restrict__ comb,
    unsigned short* __restrict__ HT, float* __restrict__ out) {
  __shared__ float red[4][16][NCLS];
  const int tid = threadIdx.x, wv = tid >> 6, lane = tid & 63;
  const int lr = lane & 15, lg = lane >> 4;
  const int r0 = blockIdx.x * 16;
  int cm[4], cn[4];
  calib_mn(lane, cm, cn);

  f32x4 acc[4];
#pragma unroll
  for (int t = 0; t < 4; ++t)
#pragma unroll
    for (int j = 0; j < 4; ++j) acc[t][j] = 0.f;

  const int kg = wv * 32 + 8 * lg;
  const s16x8 af = *(const s16x8*)(H1 + (size_t)(r0 + lr) * HID + kg);
#pragma unroll
  for (int t = 0; t < 4; ++t) {
    const s16x8 bf = *(const s16x8*)(W2T + (size_t)(16 * t + lr) * HID + kg);
    MFMA16(acc[t], af, bf);
  }
#pragma unroll
  for (int t = 0; t < 4; ++t)
#pragma unroll
    for (int r = 0; r < 4; ++r)
      red[wv][cm[r]][16 * t + cn[r]] = acc[t][r];
  __syncthreads();

  const int row = tid >> 4;
  const int c4 = (tid & 15) * 4;
#pragma unroll
  for (int j = 0; j < 4; ++j) {
    const int c = c4 + j;
    const float v = red[0][row][c] + red[1][row][c] + red[2][row][c] + red[3][row][c] + b2[c];
    out[(size_t)(r0 + row) * NCLS + c] = comb[2 * NCLS + c] * v;
    HT[(size_t)c * STRD + r0 + row] = f2bf(v);
  }
}

// ================ unified graph matmul ================
// A is wave-private (wave wv feeds only rows wv*16+lr) -> A loads go straight to
// registers (1-iter prefetch; compiler-managed waits). Only the shared B tile is
// staged through LDS (3-buf counted-vmcnt, R11-proven discipline).
// MODE 0: A bf16 (adjb), dest=Yf unscaled atomics.
// MODE 1: A f32 (filter), dest=out scaled by comb[didx].
// MODE 2: A f32 (adj), writes adjb bf16, dest=Yf unscaled atomics.
// Manual B-waits (in-order vmcnt; stores conservatively excluded from counts):
//   MODE0: u0=2, u1=3, steady=4, V-2=3, V-1=2
//   MODE1/2: u0=2, u1=4, steady=6, V-2=5, V-1=4
template <int MODE>
__global__ __launch_bounds__(256) void gmm_kernel(
    const void* __restrict__ Av, int astride,
    const unsigned short* __restrict__ BT,
    float* __restrict__ dest, const float* __restrict__ comb, int didx,
    unsigned short* __restrict__ adjb) {
  constexpr int NA = (MODE == 0) ? 1 : 2;
  __shared__ unsigned char lds[3][4096];
  const int tid = threadIdx.x, wv = tid >> 6, lane = tid & 63;
  const int lr = lane & 15, lg = lane >> 4;
  const int r0 = blockIdx.x * 64;
  const int s0 = blockIdx.y * VSTEPS;
  int cm[4], cn[4];
  calib_mn(lane, cm, cn);

  const int arow = r0 + wv * 16 + lr;
  const int gr = (arow < NN) ? arow : (NN - 1);
  const unsigned short* ab = (const unsigned short*)Av + (size_t)gr * astride;
  const float* af = (const float*)Av + (size_t)gr * astride;
  unsigned short* wout = (MODE == 2) ? (adjb + (size_t)gr * STRD) : nullptr;

  f32x4 acc[4];
#pragma unroll
  for (int t = 0; t < 4; ++t)
#pragma unroll
    for (int j = 0; j < 4; ++j) acc[t][j] = 0.f;

  auto stageB = [&](int b, int s) {
    const int k0 = s * 32;
    const int V = wv * 64 + lane;
    const int col = V >> 2, slot = V & 3;
    const int chunk = slot ^ (col & 3);
    __builtin_amdgcn_global_load_lds(BT + (size_t)col * STRD + k0 + chunk * 8,
                                     (void*)&lds[b][wv * 1024], 16, 0, 0);
  };

  s16x8 ah_cur;
  float4 af_cur0 = make_float4(0.f, 0.f, 0.f, 0.f), af_cur1 = af_cur0;
#pragma unroll
  for (int j = 0; j < 8; ++j) ah_cur[j] = 0;

  auto loadA = [&](int s, s16x8& ah, float4& f0, float4& f1) {
    const int kg = s * 32 + 8 * lg;
    if (MODE == 0) {
      ah = *(const s16x8*)(ab + kg);  // adjb: padded cols pre-zeroed by MODE2 pass
    } else {
      if (kg + 8 <= NN) {
        f0 = *(const float4*)(af + kg);
        f1 = *(const float4*)(af + kg + 4);
      } else {
        f0 = make_float4(0.f, 0.f, 0.f, 0.f);
        f1 = f0;
      }
    }
  };

  // prologue: A(0) first (older than all DMAs), then B DMAs for steps 0..2
  loadA(s0, ah_cur, af_cur0, af_cur1);
  stageB(0, s0); stageB(1, s0 + 1); stageB(2, s0 + 2);

  int bi = 0;
  for (int u = 0; u < VSTEPS; ++u) {
    if (u == 0)                 vmwait(2);
    else if (u == 1)            vmwait(MODE == 0 ? 3 : 4);
    else if (u < VSTEPS - 2)    vmwait(MODE == 0 ? 4 : 6);
    else if (u == VSTEPS - 2)   vmwait(MODE == 0 ? 3 : 5);
    else                        vmwait(MODE == 0 ? 2 : 4);
    __builtin_amdgcn_sched_barrier(0);
    __builtin_amdgcn_s_barrier();  // all waves' B(u) DMA landed
    FENCE_ANCHOR();
    {
      // prefetch A(u+1) into regs (wave-private; compiler inserts its own wait
      // before next iter's use -> 1 full iteration of latency hiding)
      s16x8 ah_nxt;
      float4 af_nxt0, af_nxt1;
      if (u + 1 < VSTEPS) loadA(s0 + u + 1, ah_nxt, af_nxt0, af_nxt1);
      s16x8 afr;
      if (MODE == 0) {
        afr = ah_cur;
      } else {
        afr[0] = (short)f2bf(af_cur0.x); afr[1] = (short)f2bf(af_cur0.y);
        afr[2] = (short)f2bf(af_cur0.z); afr[3] = (short)f2bf(af_cur0.w);
        afr[4] = (short)f2bf(af_cur1.x); afr[5] = (short)f2bf(af_cur1.y);
        afr[6] = (short)f2bf(af_cur1.z); afr[7] = (short)f2bf(af_cur1.w);
      }
      if (MODE == 2) *(s16x8*)(wout + (s0 + u) * 32 + 8 * lg) = afr;  // adjb writeback (zeros pad)
      const unsigned char* L = lds[bi];
#pragma unroll
      for (int t = 0; t < 4; ++t) {
        const int col = t * 16 + lr;
        const s16x8 bf = *(const s16x8*)(L + col * 64 + ((lg ^ (col & 3)) << 4));
        MFMA16(acc[t], afr, bf);
      }
      if (u + 1 < VSTEPS) {
        ah_cur = ah_nxt; af_cur0 = af_nxt0; af_cur1 = af_nxt1;
      }
    }
    asm volatile("s_waitcnt lgkmcnt(0)" ::: "memory");  // my ds_reads done
    __builtin_amdgcn_sched_barrier(0);
    __builtin_amdgcn_s_barrier();  // all waves done reading buf bi
    FENCE_ANCHOR();
    if (u + 3 < VSTEPS) stageB(bi, s0 + u + 3);
    bi = (bi == 2) ? 0 : bi + 1;
  }

#pragma unroll
  for (int t = 0; t < 4; ++t) {
#pragma unroll
    for (int q = 0; q < 4; ++q) {
      const int c = 16 * t + cn[q];
      const int r = r0 + wv * 16 + cm[q];
      if (r < NN) {
        if (MODE == 1)
          atomicAdd(&dest[(size_t)r * NCLS + c], comb[didx * NCLS + c] * acc[t][q]);
        else
          atomicAdd(&dest[(size_t)r * NCLS + c], acc[t][q]);
      }
    }
  }
}

// ---------------- finish: out += comb*Yf, PT = bf16(Yf^T), Yf = 0 ----------------
__global__ __launch_bounds__(256) void finish_old_kernel(
    float* __restrict__ Yf, const float* __restrict__ comb, int didx,
    unsigned short* __restrict__ PT, float* __restrict__ out) {
  __shared__ float ysh[32][65];
  const int tid = threadIdx.x;
  const int r0 = blockIdx.x * 32;
#pragma unroll
  for (int j = 0; j < 8; ++j) {
    const int idx = j * 256 + tid;
    const int rr = idx >> 6;
    const int c = idx & 63;
    const int r = r0 + rr;
    if (r < NN) {
      const float y = Yf[(size_t)r * NCLS + c];
      Yf[(size_t)r * NCLS + c] = 0.f;
      ysh[rr][c] = y;
      out[(size_t)r * NCLS + c] += comb[didx * NCLS + c] * y;
    }
  }
  __syncthreads();
  const int c = tid >> 2;
  const int rr = (tid & 3) * 8;
  if (r0 + rr + 7 < NN) {
    ushort4 u0 = make_ushort4(f2bf(ysh[rr + 0][c]), f2bf(ysh[rr + 1][c]),
                              f2bf(ysh[rr + 2][c]), f2bf(ysh[rr + 3][c]));
    ushort4 u1 = make_ushort4(f2bf(ysh[rr + 4][c]), f2bf(ysh[rr + 5][c]),
                              f2bf(ysh[rr + 6][c]), f2bf(ysh[rr + 7][c]));
    *(ushort4*)(PT + (size_t)c * STRD + r0 + rr) = u0;
    *(ushort4*)(PT + (size_t)c * STRD + r0 + rr + 4) = u1;
  }
}

extern "C" void kernel_launch(void* const* d_in, const int* in_sizes, int n_in,
                              void* d_out, int out_size, void* d_ws, size_t ws_size,
                              hipStream_t stream) {
  const float* x = (const float*)d_in[0];
  const float* adj = (const float*)d_in[1];
  const float* filt0 = (const float*)d_in[2];
  const float* filt1 = (const float*)d_in[3];
  const float* W1 = (const float*)d_in[4];
  const float* b1 = (const float*)d_in[5];
  const float* W2 = (const float*)d_in[6];
  const float* b2 = (const float*)d_in[7];
  const float* comb = (const float*)d_in[8];
  float* out = (float*)d_out;

  unsigned char* wsb = (unsigned char*)d_ws;
  size_t off = 0;
  auto carve = [&](size_t bytes) -> void* {
    void* p = wsb + off;
    off += (bytes + 255) & ~(size_t)255;
    return p;
  };
  unsigned short* W1T = (unsigned short*)carve((size_t)FEAT * HID * 2);
  unsigned short* W2T = (unsigned short*)carve((size_t)HID * NCLS * 2);
  unsigned short* H1 = (unsigned short*)carve((size_t)NN * HID * 2);
  float* Yf = (float*)carve((size_t)NN * NCLS * 4);
  unsigned short* HT = (unsigned short*)carve((size_t)NCLS * STRD * 2);
  unsigned short* pA = (unsigned short*)carve((size_t)NCLS * STRD * 2);
  unsigned short* pB = (unsigned short*)carve((size_t)NCLS * STRD * 2);
  unsigned short* adjb = (unsigned short*)carve((size_t)NN * STRD * 2);

  if (ws_size < off) {
    // Sentinel: absmax == 5.40625 exactly => ws too small.
    zero_f32_kernel<<<(out_size + 255) / 256, 256, 0, stream>>>(out, out_size);
    return;
  }

  zero_f32_kernel<<<(NN * NCLS + 255) / 256, 256, 0, stream>>>(Yf, NN * NCLS);
  prep_kernel<<<(FEAT * HID + 255) / 256, 256, 0, stream>>>(W1, W2, W1T, W2T, HT, pA, pB);
  mlp1_kernel<<<(NN + 15) / 16, 256, 0, stream>>>(x, W1T, b1, H1);
  mlp2_kernel<<<(NN + 15) / 16, 256, 0, stream>>>(H1, W2T, b2, comb, HT, out);

  const dim3 gg(157, KSPLIT);
  // filters: f32 A -> registers, scaled atomics into out
  gmm_kernel<1><<<gg, 256, 0, stream>>>(filt0, NN, HT, out, comb, 0, nullptr);
  gmm_kernel<1><<<gg, 256, 0, stream>>>(filt1, NN, HT, out, comb, 1, nullptr);

  // k=1: f32 adj -> registers, writes adjb bf16, partials into Yf
  gmm_kernel<2><<<gg, 256, 0, stream>>>(adj, NN, HT, Yf, comb, 0, adjb);
  finish_old_kernel<<<313, 256, 0, stream>>>(Yf, comb, 3, pA, out);

  const unsigned short* pin = pA;
  for (int k = 2; k <= 10; ++k) {
    unsigned short* pout = (k & 1) ? pA : pB;
    gmm_kernel<0><<<gg, 256, 0, stream>>>(adjb, STRD, pin, Yf, comb, 0, nullptr);
    finish_old_kernel<<<313, 256, 0, stream>>>(Yf, comb, 2 + k, pout, out);
    pin = pout;
  }
}

// Round 15
// 986.078 us; speedup vs baseline: 1.3388x; 1.3388x over previous
//
#include <hip/hip_runtime.h>

#define NN 10000
#define STRD 10272  // bf16 panel/adjb row stride (elements)
#define KSPLIT 16   // K-slices
#define VSTEPS 20   // K-steps of 32 per block
#define FEAT 2048
#define HID 128
#define NCLS 64

typedef short s16x8 __attribute__((ext_vector_type(8)));
typedef float f32x4 __attribute__((ext_vector_type(4)));

static __device__ __forceinline__ unsigned short f2bf(float f) {
  unsigned int u = __float_as_uint(f);
  u += 0x7FFFu + ((u >> 16) & 1u);
  return (unsigned short)(u >> 16);
}

#define MFMA16(accv, av, bv) \
  (accv) = __builtin_amdgcn_mfma_f32_16x16x32_bf16((av), (bv), (accv), 0, 0, 0)

#define FENCE_ANCHOR() do { asm volatile("" ::: "memory"); __builtin_amdgcn_sched_barrier(0); } while (0)

__device__ __forceinline__ void vmwait(int n) {
  switch (n) {
    case 0: asm volatile("s_waitcnt vmcnt(0)" ::: "memory"); break;
    case 2: asm volatile("s_waitcnt vmcnt(2)" ::: "memory"); break;
    case 3: asm volatile("s_waitcnt vmcnt(3)" ::: "memory"); break;
    case 4: asm volatile("s_waitcnt vmcnt(4)" ::: "memory"); break;
    default: asm volatile("s_waitcnt vmcnt(5)" ::: "memory"); break;
  }
}

// Self-calibration of the MFMA C/D lane->(m,n) mapping (proved correct in R2).
__device__ __forceinline__ void calib_mn(int lane, int* cm, int* cn) {
  const int lr = lane & 15;
  const int lg = lane >> 4;
  s16x8 pa, pb;
#pragma unroll
  for (int j = 0; j < 8; ++j) { pa[j] = 0; pb[j] = 0; }
  if (lg == 0) {
    pa[0] = (short)f2bf(1.0f);
    pa[1] = (short)f2bf((float)(1 + lr));
    pb[0] = (short)f2bf((float)(128 * (1 + lr)));
    pb[1] = (short)f2bf(1.0f);
  }
  f32x4 acc;
#pragma unroll
  for (int j = 0; j < 4; ++j) acc[j] = 0.f;
  MFMA16(acc, pa, pb);
#pragma unroll
  for (int r = 0; r < 4; ++r) {
    const int v = (int)acc[r];
    cm[r] = (v & 127) - 1;
    cn[r] = (v >> 7) - 1;
  }
}

__global__ void zero_f32_kernel(float* __restrict__ p, int n) {
  int i = blockIdx.x * 256 + threadIdx.x;
  if (i < n) p[i] = 0.f;
}

// prep: transpose W1, W2 to bf16; zero pad columns of the 3 bf16 p-panels
__global__ void prep_kernel(const float* __restrict__ W1, const float* __restrict__ W2,
                            unsigned short* __restrict__ W1T, unsigned short* __restrict__ W2T,
                            unsigned short* __restrict__ HT, unsigned short* __restrict__ pA,
                            unsigned short* __restrict__ pB) {
  const int idx = blockIdx.x * 256 + threadIdx.x;
  if (idx < FEAT * HID) {
    const int k = idx / HID, c = idx % HID;
    W1T[(size_t)c * FEAT + k] = f2bf(W1[idx]);
  }
  if (idx < HID * NCLS) {
    const int k = idx / NCLS, c = idx % NCLS;
    W2T[(size_t)c * HID + k] = f2bf(W2[idx]);
  }
  if (idx < 3 * 64 * (STRD - NN)) {
    const int span = 64 * (STRD - NN);
    const int p = idx / span;
    const int rem = idx % span;
    const int c = rem / (STRD - NN);
    const int col = NN + rem % (STRD - NN);
    unsigned short* pan = (p == 0) ? HT : ((p == 1) ? pA : pB);
    pan[(size_t)c * STRD + col] = 0;
  }
}

// ---------------- MLP layer 1 ----------------
__global__ __launch_bounds__(256) void mlp1_kernel(
    const float* __restrict__ X, const unsigned short* __restrict__ W1T,
    const float* __restrict__ b1, unsigned short* __restrict__ H1) {
  __shared__ float red[4][16][HID];
  const int tid = threadIdx.x, wv = tid >> 6, lane = tid & 63;
  const int lr = lane & 15, lg = lane >> 4;
  const int r0 = blockIdx.x * 16;
  int cm[4], cn[4];
  calib_mn(lane, cm, cn);

  f32x4 acc[8];
#pragma unroll
  for (int t = 0; t < 8; ++t)
#pragma unroll
    for (int j = 0; j < 4; ++j) acc[t][j] = 0.f;

  for (int s = wv * 16; s < wv * 16 + 16; ++s) {
    const int kg = s * 32 + 8 * lg;
    const float* px = X + (size_t)(r0 + lr) * FEAT + kg;
    const float4 xa = *(const float4*)(px);
    const float4 xb = *(const float4*)(px + 4);
    s16x8 af;
    af[0] = (short)f2bf(xa.x); af[1] = (short)f2bf(xa.y);
    af[2] = (short)f2bf(xa.z); af[3] = (short)f2bf(xa.w);
    af[4] = (short)f2bf(xb.x); af[5] = (short)f2bf(xb.y);
    af[6] = (short)f2bf(xb.z); af[7] = (short)f2bf(xb.w);
#pragma unroll
    for (int t = 0; t < 8; ++t) {
      const s16x8 bf = *(const s16x8*)(W1T + (size_t)(16 * t + lr) * FEAT + kg);
      MFMA16(acc[t], af, bf);
    }
  }
#pragma unroll
  for (int t = 0; t < 8; ++t)
#pragma unroll
    for (int r = 0; r < 4; ++r)
      red[wv][cm[r]][16 * t + cn[r]] = acc[t][r];
  __syncthreads();

  const int row = tid >> 4;
  const int c0 = (tid & 15) * 8;
  s16x8 hv;
#pragma unroll
  for (int j = 0; j < 8; ++j) {
    float v = red[0][row][c0 + j] + red[1][row][c0 + j] +
              red[2][row][c0 + j] + red[3][row][c0 + j] + b1[c0 + j];
    v = fmaxf(v, 0.f);
    hv[j] = (short)f2bf(v);
  }
  *(s16x8*)(H1 + (size_t)(r0 + row) * HID + c0) = hv;
}

// ---------------- MLP layer 2 -> HT (bf16 64 x STRD) + out init ----------------
__global__ __launch_bounds__(256) void mlp2_kernel(
    const unsigned short* __restrict__ H1, const unsigned short* __restrict__ W2T,
    const float* __restrict__ b2, const float* __restrict__ comb,
    unsigned short* __restrict__ HT, float* __restrict__ out) {
  __shared__ float red[4][16][NCLS];
  const int tid = threadIdx.x, wv = tid >> 6, lane = tid & 63;
  const int lr = lane & 15, lg = lane >> 4;
  const int r0 = blockIdx.x * 16;
  int cm[4], cn[4];
  calib_mn(lane, cm, cn);

  f32x4 acc[4];
#pragma unroll
  for (int t = 0; t < 4; ++t)
#pragma unroll
    for (int j = 0; j < 4; ++j) acc[t][j] = 0.f;

  const int kg = wv * 32 + 8 * lg;
  const s16x8 af = *(const s16x8*)(H1 + (size_t)(r0 + lr) * HID + kg);
#pragma unroll
  for (int t = 0; t < 4; ++t) {
    const s16x8 bf = *(const s16x8*)(W2T + (size_t)(16 * t + lr) * HID + kg);
    MFMA16(acc[t], af, bf);
  }
#pragma unroll
  for (int t = 0; t < 4; ++t)
#pragma unroll
    for (int r = 0; r < 4; ++r)
      red[wv][cm[r]][16 * t + cn[r]] = acc[t][r];
  __syncthreads();

  const int row = tid >> 4;
  const int c4 = (tid & 15) * 4;
#pragma unroll
  for (int j = 0; j < 4; ++j) {
    const int c = c4 + j;
    const float v = red[0][row][c] + red[1][row][c] + red[2][row][c] + red[3][row][c] + b2[c];
    out[(size_t)(r0 + row) * NCLS + c] = comb[2 * NCLS + c] * v;
    HT[(size_t)c * STRD + r0 + row] = f2bf(v);
  }
}

// ================ gmm2: bf16 power pass — M=64, 3-buf counted-vmcnt (R11-proven) ============
// grid (157, 16). LDS 3 x 8KB. Swizzle f(x) = (x>>1)&3 -> 2-way (free) LDS reads.
__global__ __launch_bounds__(256) void gmm2_kernel(
    const unsigned short* __restrict__ Ab, const unsigned short* __restrict__ BT,
    float* __restrict__ Yf) {
  __shared__ unsigned char lds[3][8192];
  const int tid = threadIdx.x, wv = tid >> 6, lane = tid & 63;
  const int lr = lane & 15, lg = lane >> 4;
  const int r0 = blockIdx.x * 64;
  const int s0 = blockIdx.y * VSTEPS;
  int cm[4], cn[4];
  calib_mn(lane, cm, cn);

  f32x4 acc[4];
#pragma unroll
  for (int t = 0; t < 4; ++t)
#pragma unroll
    for (int j = 0; j < 4; ++j) acc[t][j] = 0.f;

  auto stage = [&](int b, int s) {
    const int k0 = s * 32;
    {  // A: 256 16B-units (4/row)
      const int U = wv * 64 + lane;
      const int row = U >> 2, slot = U & 3;
      const int chunk = slot ^ ((row >> 1) & 3);
      const int gr = (r0 + row < NN) ? (r0 + row) : (NN - 1);
      __builtin_amdgcn_global_load_lds(Ab + (size_t)gr * STRD + k0 + chunk * 8,
                                       (void*)&lds[b][wv * 1024], 16, 0, 0);
    }
    {  // B: 256 16B-units (4/col)
      const int V = wv * 64 + lane;
      const int col = V >> 2, slot = V & 3;
      const int chunk = slot ^ ((col >> 1) & 3);
      __builtin_amdgcn_global_load_lds(BT + (size_t)col * STRD + k0 + chunk * 8,
                                       (void*)&lds[b][4096 + wv * 1024], 16, 0, 0);
    }
  };

  stage(0, s0); stage(1, s0 + 1); stage(2, s0 + 2);

  int bi = 0;
  for (int u = 0; u < VSTEPS; ++u) {
    if (u + 2 < VSTEPS)      vmwait(4);
    else if (u + 1 < VSTEPS) vmwait(2);
    else                     vmwait(0);
    __builtin_amdgcn_sched_barrier(0);
    __builtin_amdgcn_s_barrier();  // all waves' stage-u DMA landed
    FENCE_ANCHOR();
    {
      const unsigned char* L = lds[bi];
      const int row = wv * 16 + lr;
      const s16x8 af = *(const s16x8*)(L + row * 64 + ((lg ^ ((row >> 1) & 3)) << 4));
#pragma unroll
      for (int t = 0; t < 4; ++t) {
        const int col = t * 16 + lr;
        const s16x8 bf = *(const s16x8*)(L + 4096 + col * 64 + ((lg ^ ((col >> 1) & 3)) << 4));
        MFMA16(acc[t], af, bf);
      }
    }
    asm volatile("s_waitcnt lgkmcnt(0)" ::: "memory");  // my ds_reads done
    __builtin_amdgcn_sched_barrier(0);
    __builtin_amdgcn_s_barrier();  // all waves done reading buf bi
    FENCE_ANCHOR();
    if (u + 3 < VSTEPS) stage(bi, s0 + u + 3);  // loads fly across barriers
    bi = (bi == 2) ? 0 : bi + 1;
  }

#pragma unroll
  for (int t = 0; t < 4; ++t) {
#pragma unroll
    for (int q = 0; q < 4; ++q) {
      const int c = 16 * t + cn[q];
      const int r = r0 + wv * 16 + cm[q];
      if (r < NN) atomicAdd(&Yf[(size_t)r * NCLS + c], acc[t][q]);
    }
  }
}

// ================ gmmf: f32-A pass — 2-buf counted-vmcnt ================
// FM=0: filters, grid (157,16,2), z selects A + comb row; scaled atomics into out.
// FM=1: adj k=1, grid (157,16); writes adjb bf16 during compute; Yf atomics.
// waits (stores counted in-order): FM0: u0=3, steady=3, last=0. FM1: u0=3, steady=5, last=2.
template <int FM>
__global__ __launch_bounds__(256) void gmmf_kernel(
    const float* __restrict__ A0, const float* __restrict__ A1,
    const unsigned short* __restrict__ BT, float* __restrict__ dest,
    const float* __restrict__ comb, unsigned short* __restrict__ adjb) {
  __shared__ unsigned char lds[2][12288];  // [buf][A f32 8KB | B bf16 4KB]
  const int tid = threadIdx.x, wv = tid >> 6, lane = tid & 63;
  const int lr = lane & 15, lg = lane >> 4;
  const int r0 = blockIdx.x * 64;
  const int s0 = blockIdx.y * VSTEPS;
  const float* A = (FM == 0 && blockIdx.z) ? A1 : A0;
  int cm[4], cn[4];
  calib_mn(lane, cm, cn);

  f32x4 acc[4];
#pragma unroll
  for (int t = 0; t < 4; ++t)
#pragma unroll
    for (int j = 0; j < 4; ++j) acc[t][j] = 0.f;

  const size_t alim = (size_t)NN * NN - 4;
  const int arow = r0 + wv * 16 + lr;

  auto stage = [&](int b, int s) {
    const int k0 = s * 32;
#pragma unroll
    for (int i = 0; i < 2; ++i) {  // A f32: 512 units (8/row), chunk = slot ^ (row&7)
      const int U = i * 256 + wv * 64 + lane;
      const int row = U >> 3, slot = U & 7;
      const int chunk = slot ^ (row & 7);
      const int gr = (r0 + row < NN) ? (r0 + row) : (NN - 1);
      size_t off = (size_t)gr * NN + k0 + chunk * 4;
      if (off > alim) off = alim;  // k-pad clamp; B pad zeros kill the product
      __builtin_amdgcn_global_load_lds(A + off,
                                       (void*)&lds[b][(i * 256 + wv * 64) * 16], 16, 0, 0);
    }
    {  // B bf16: 256 units (4/col), chunk = slot ^ ((col>>1)&3)
      const int V = wv * 64 + lane;
      const int col = V >> 2, slot = V & 3;
      const int chunk = slot ^ ((col >> 1) & 3);
      __builtin_amdgcn_global_load_lds(BT + (size_t)col * STRD + k0 + chunk * 8,
                                       (void*)&lds[b][8192 + wv * 1024], 16, 0, 0);
    }
  };

  stage(0, s0); stage(1, s0 + 1);

  int bi = 0;
  for (int u = 0; u < VSTEPS; ++u) {
    if (u == 0)              vmwait(3);
    else if (u + 1 < VSTEPS) vmwait(FM == 0 ? 3 : 5);
    else                     vmwait(FM == 0 ? 0 : 2);
    __builtin_amdgcn_sched_barrier(0);
    __builtin_amdgcn_s_barrier();
    FENCE_ANCHOR();
    {
      const unsigned char* L = lds[bi];
      const int row = wv * 16 + lr;
      s16x8 af;
#pragma unroll
      for (int d = 0; d < 2; ++d) {
        const int c = 2 * lg + d;
        const int chunk = c ^ (row & 7);
        const float4 f = *(const float4*)(L + row * 128 + (chunk << 4));
        ushort4 ub;
        ub.x = f2bf(f.x); ub.y = f2bf(f.y); ub.z = f2bf(f.z); ub.w = f2bf(f.w);
        af[4 * d + 0] = (short)ub.x; af[4 * d + 1] = (short)ub.y;
        af[4 * d + 2] = (short)ub.z; af[4 * d + 3] = (short)ub.w;
        if (FM == 1 && arow < NN) {
          // FIX (R13/R14 bug): data read is global chunk c (swizzle cancels on
          // read) -> write to column c*4, NOT chunk*4.
          *(ushort4*)(adjb + (size_t)arow * STRD + (s0 + u) * 32 + c * 4) = ub;
        }
      }
#pragma unroll
      for (int t = 0; t < 4; ++t) {
        const int col = t * 16 + lr;
        const s16x8 bf = *(const s16x8*)(L + 8192 + col * 64 + ((lg ^ ((col >> 1) & 3)) << 4));
        MFMA16(acc[t], af, bf);
      }
    }
    asm volatile("s_waitcnt lgkmcnt(0)" ::: "memory");
    __builtin_amdgcn_sched_barrier(0);
    __builtin_amdgcn_s_barrier();
    FENCE_ANCHOR();
    if (u + 2 < VSTEPS) stage(bi, s0 + u + 2);
    bi ^= 1;
  }

#pragma unroll
  for (int t = 0; t < 4; ++t) {
#pragma unroll
    for (int q = 0; q < 4; ++q) {
      const int c = 16 * t + cn[q];
      const int r = r0 + wv * 16 + cm[q];
      if (r < NN) {
        if (FM == 0)
          atomicAdd(&dest[(size_t)r * NCLS + c],
                    comb[blockIdx.z * NCLS + c] * acc[t][q]);
        else
          atomicAdd(&dest[(size_t)r * NCLS + c], acc[t][q]);
      }
    }
  }
}

// ---------------- finish: out += comb*Yf, PT = bf16(Yf^T), Yf = 0 ----------------
__global__ __launch_bounds__(256) void finish_old_kernel(
    float* __restrict__ Yf, const float* __restrict__ comb, int didx,
    unsigned short* __restrict__ PT, float* __restrict__ out) {
  __shared__ float ysh[32][65];
  const int tid = threadIdx.x;
  const int r0 = blockIdx.x * 32;
#pragma unroll
  for (int j = 0; j < 8; ++j) {
    const int idx = j * 256 + tid;
    const int rr = idx >> 6;
    const int c = idx & 63;
    const int r = r0 + rr;
    if (r < NN) {
      const float y = Yf[(size_t)r * NCLS + c];
      Yf[(size_t)r * NCLS + c] = 0.f;
      ysh[rr][c] = y;
      out[(size_t)r * NCLS + c] += comb[didx * NCLS + c] * y;
    }
  }
  __syncthreads();
  const int c = tid >> 2;
  const int rr = (tid & 3) * 8;
  if (r0 + rr + 7 < NN) {
    ushort4 u0 = make_ushort4(f2bf(ysh[rr + 0][c]), f2bf(ysh[rr + 1][c]),
                              f2bf(ysh[rr + 2][c]), f2bf(ysh[rr + 3][c]));
    ushort4 u1 = make_ushort4(f2bf(ysh[rr + 4][c]), f2bf(ysh[rr + 5][c]),
                              f2bf(ysh[rr + 6][c]), f2bf(ysh[rr + 7][c]));
    *(ushort4*)(PT + (size_t)c * STRD + r0 + rr) = u0;
    *(ushort4*)(PT + (size_t)c * STRD + r0 + rr + 4) = u1;
  }
}

extern "C" void kernel_launch(void* const* d_in, const int* in_sizes, int n_in,
                              void* d_out, int out_size, void* d_ws, size_t ws_size,
                              hipStream_t stream) {
  const float* x = (const float*)d_in[0];
  const float* adj = (const float*)d_in[1];
  const float* filt0 = (const float*)d_in[2];
  const float* filt1 = (const float*)d_in[3];
  const float* W1 = (const float*)d_in[4];
  const float* b1 = (const float*)d_in[5];
  const float* W2 = (const float*)d_in[6];
  const float* b2 = (const float*)d_in[7];
  const float* comb = (const float*)d_in[8];
  float* out = (float*)d_out;

  unsigned char* wsb = (unsigned char*)d_ws;
  size_t off = 0;
  auto carve = [&](size_t bytes) -> void* {
    void* p = wsb + off;
    off += (bytes + 255) & ~(size_t)255;
    return p;
  };
  unsigned short* W1T = (unsigned short*)carve((size_t)FEAT * HID * 2);
  unsigned short* W2T = (unsigned short*)carve((size_t)HID * NCLS * 2);
  unsigned short* H1 = (unsigned short*)carve((size_t)NN * HID * 2);
  float* Yf = (float*)carve((size_t)NN * NCLS * 4);
  unsigned short* HT = (unsigned short*)carve((size_t)NCLS * STRD * 2);
  unsigned short* pA = (unsigned short*)carve((size_t)NCLS * STRD * 2);
  unsigned short* pB = (unsigned short*)carve((size_t)NCLS * STRD * 2);
  unsigned short* adjb = (unsigned short*)carve((size_t)NN * STRD * 2);

  if (ws_size < off) {
    // Sentinel: absmax == 5.40625 exactly => ws too small.
    zero_f32_kernel<<<(out_size + 255) / 256, 256, 0, stream>>>(out, out_size);
    return;
  }

  zero_f32_kernel<<<(NN * NCLS + 255) / 256, 256, 0, stream>>>(Yf, NN * NCLS);
  prep_kernel<<<(FEAT * HID + 255) / 256, 256, 0, stream>>>(W1, W2, W1T, W2T, HT, pA, pB);
  mlp1_kernel<<<(NN + 15) / 16, 256, 0, stream>>>(x, W1T, b1, H1);
  mlp2_kernel<<<(NN + 15) / 16, 256, 0, stream>>>(H1, W2T, b2, comb, HT, out);

  // filters: f32 A via LDS, scaled atomics into out
  gmmf_kernel<0><<<dim3(157, KSPLIT, 2), 256, 0, stream>>>(
      filt0, filt1, HT, out, comb, nullptr);

  // k=1: f32 adj, adjb writeback fused; partials into Yf
  gmmf_kernel<1><<<dim3(157, KSPLIT), 256, 0, stream>>>(
      adj, adj, HT, Yf, comb, adjb);
  finish_old_kernel<<<313, 256, 0, stream>>>(Yf, comb, 3, pA, out);

  const unsigned short* pin = pA;
  for (int k = 2; k <= 10; ++k) {
    unsigned short* pout = (k & 1) ? pA : pB;
    gmm2_kernel<<<dim3(157, KSPLIT), 256, 0, stream>>>(adjb, pin, Yf);
    finish_old_kernel<<<313, 256, 0, stream>>>(Yf, comb, 2 + k, pout, out);
    pin = pout;
  }
}